// Round 9
// baseline (103.230 us; speedup 1.0000x reference)
//
#include <hip/hip_runtime.h>

#define NAG   8192
#define NK    4096
#define BLOCK 256
#define ROWS  4            // agents per thread (register blocking)
#define CHUNK 64           // j-points staged per block
#define NCK   (NAG / CHUNK)   // 128 KDE chunks
#define NCG   (NK  / CHUNK)   // 64 GMM chunks
#define AGB   (BLOCK * ROWS)  // 1024 agents per block

// Pre-scale trick: exp(-d2/(2h^2)) = exp2(-|sK*dx|^2), sK = sqrt(log2e/(2h^2)).
// h = 0.05  -> sK = 16.98643615 ; s = 5/64 -> sG = 10.87131904
#define SK_SCALE 16.98643615f
#define SG_SCALE 10.87131904f
// out = (B/h^2 - C*N*h^2/s^4 + F*N*h^2/s^2)/A with B,C in prescaled coords:
#define SC_B   (23.5482041f)    // (1/h^2)/sK
#define SC_C   (50569.375f)     // (N*h^2/s^4)/sG
#define SC_F   (3355.4432f)     // N*h^2/s^2

typedef float f32x2 __attribute__((ext_vector_type(2)));

// VOP3P packed-f32: ALL vector operands must be 64-bit VGPR pairs on gfx950.
// (A scalar src with op_sel_hi broadcast is an invalid operand — R8 compile error.)
__device__ __forceinline__ f32x2 pk_add(f32x2 a, f32x2 b) {
  f32x2 d; asm("v_pk_add_f32 %0, %1, %2" : "=v"(d) : "v"(a), "v"(b)); return d;
}
__device__ __forceinline__ f32x2 pk_mul(f32x2 a, f32x2 b) {
  f32x2 d; asm("v_pk_mul_f32 %0, %1, %2" : "=v"(d) : "v"(a), "v"(b)); return d;
}
__device__ __forceinline__ f32x2 pk_fma(f32x2 a, f32x2 b, f32x2 c) {
  f32x2 d; asm("v_pk_fma_f32 %0, %1, %2, %3" : "=v"(d) : "v"(a), "v"(b), "v"(c));
  return d;
}
__device__ __forceinline__ f32x2 bcast(float a) { return (f32x2){a, a}; }

// ws: pK float4[NCK][NAG] (16 MB)  {A, Bx', By', 0}
//     pG float4[NCG][NAG] ( 8 MB)  {Cx', Cy', Fx, Fy}
__global__ __launch_bounds__(BLOCK) void wm_pair_kernel(
    const float*  __restrict__ t,
    const float2* __restrict__ X,
    const float2* __restrict__ m0,
    const float2* __restrict__ mv,
    const float*  __restrict__ w,
    float4* __restrict__ pK,
    float4* __restrict__ pG) {
  __shared__ f32x2 sNP[CHUNK];   // negated prescaled point (KDE: -sK*Xj, GMM: -sG*m)
  __shared__ f32x2 sMV[CHUNK];   // GMM: mv
  __shared__ float sW[CHUNK];    // GMM: w

  const int iBase = blockIdx.x * AGB + threadIdx.x;
  const int c = blockIdx.y;

  if (c < NCK) {
    // ---------------- KDE chunk ----------------
    const int base = c * CHUNK;
    if (threadIdx.x < CHUNK) {
      const float2 xj = X[base + threadIdx.x];
      sNP[threadIdx.x] = (f32x2){-SK_SCALE * xj.x, -SK_SCALE * xj.y};
    }
    __syncthreads();

    f32x2 xi[ROWS];
#pragma unroll
    for (int r = 0; r < ROWS; ++r) {
      const float2 v = X[iBase + r * BLOCK];
      xi[r] = (f32x2){SK_SCALE * v.x, SK_SCALE * v.y};
    }
    float A[ROWS];
    f32x2 B[ROWS];
#pragma unroll
    for (int r = 0; r < ROWS; ++r) { A[r] = 0.f; B[r] = (f32x2){0.f, 0.f}; }

#pragma unroll 4
    for (int j = 0; j < CHUNK; ++j) {
      const f32x2 p = sNP[j];                      // one ds_read_b64, reused 4x
#pragma unroll
      for (int r = 0; r < ROWS; ++r) {
        const f32x2 pd = pk_add(xi[r], p);         // sK*(Xi - Xj)
        const f32x2 sq = pk_mul(pd, pd);
        const float e  = __builtin_amdgcn_exp2f(-(sq.x + sq.y)); // neg folds into src mod
        A[r] += e;
        B[r] = pk_fma(bcast(e), pd, B[r]);
      }
    }
#pragma unroll
    for (int r = 0; r < ROWS; ++r)
      pK[c * NAG + iBase + r * BLOCK] = make_float4(A[r], B[r].x, B[r].y, 0.f);
  } else {
    // ---------------- GMM chunk ----------------
    const int cg = c - NCK;
    const int base = cg * CHUNK;
    if (threadIdx.x < CHUNK) {
      const float tt = t[0];
      const int j = base + threadIdx.x;
      const float2 m0j = m0[j];
      const float2 mvj = mv[j];
      sNP[threadIdx.x] = (f32x2){-SG_SCALE * __builtin_fmaf(mvj.x, tt, m0j.x),
                                 -SG_SCALE * __builtin_fmaf(mvj.y, tt, m0j.y)};
      sMV[threadIdx.x] = (f32x2){mvj.x, mvj.y};
      sW[threadIdx.x]  = w[j];
    }
    __syncthreads();

    f32x2 xg[ROWS];
#pragma unroll
    for (int r = 0; r < ROWS; ++r) {
      const float2 v = X[iBase + r * BLOCK];
      xg[r] = (f32x2){SG_SCALE * v.x, SG_SCALE * v.y};
    }
    f32x2 C[ROWS], F[ROWS];
#pragma unroll
    for (int r = 0; r < ROWS; ++r) { C[r] = (f32x2){0.f, 0.f}; F[r] = (f32x2){0.f, 0.f}; }

#pragma unroll 4
    for (int j = 0; j < CHUNK; ++j) {
      const f32x2 p  = sNP[j];
      const f32x2 mj = sMV[j];
      const float wj = sW[j];
#pragma unroll
      for (int r = 0; r < ROWS; ++r) {
        const f32x2 pd = pk_add(xg[r], p);         // sG*(Xi - m)
        const f32x2 sq = pk_mul(pd, pd);
        const float g  = __builtin_amdgcn_exp2f(-(sq.x + sq.y));
        const f32x2 wg = bcast(wj * g);
        C[r] = pk_fma(wg, pd, C[r]);
        F[r] = pk_fma(wg, mj, F[r]);
      }
    }
#pragma unroll
    for (int r = 0; r < ROWS; ++r)
      pG[cg * NAG + iBase + r * BLOCK] = make_float4(C[r].x, C[r].y, F[r].x, F[r].y);
  }
}

__global__ __launch_bounds__(64) void wm_final_kernel(
    const float4* __restrict__ pK, const float4* __restrict__ pG,
    float2* __restrict__ out) {
  const int i = blockIdx.x * 64 + threadIdx.x;   // 128 blocks x 64 threads = 8192
  float A = 0.f, Bx = 0.f, By = 0.f;
#pragma unroll 8
  for (int c = 0; c < NCK; ++c) {
    const float4 v = pK[c * NAG + i];
    A += v.x; Bx += v.y; By += v.z;
  }
  float Cx = 0.f, Cy = 0.f, Fx = 0.f, Fy = 0.f;
#pragma unroll 8
  for (int c = 0; c < NCG; ++c) {
    const float4 v = pG[c * NAG + i];
    Cx += v.x; Cy += v.y; Fx += v.z; Fy += v.w;
  }
  const float invA = 1.0f / A;   // A >= 1 (self term)
  const float ox = (SC_B * Bx - SC_C * Cx + SC_F * Fx) * invA;
  const float oy = (SC_B * By - SC_C * Cy + SC_F * Fy) * invA;
  out[i] = make_float2(ox, oy);
}

extern "C" void kernel_launch(void* const* d_in, const int* in_sizes, int n_in,
                              void* d_out, int out_size, void* d_ws, size_t ws_size,
                              hipStream_t stream) {
  const float*  t  = (const float*)d_in[0];
  const float2* X  = (const float2*)d_in[1];
  const float2* m0 = (const float2*)d_in[2];
  const float2* mv = (const float2*)d_in[3];
  const float*  w  = (const float*)d_in[4];
  float4* pK = (float4*)d_ws;
  float4* pG = (float4*)((char*)d_ws + (size_t)NCK * NAG * sizeof(float4));

  dim3 grid(NAG / AGB, NCK + NCG);   // 8 x 192 = 1536 blocks
  wm_pair_kernel<<<grid, BLOCK, 0, stream>>>(t, X, m0, mv, w, pK, pG);
  wm_final_kernel<<<NAG / 64, 64, 0, stream>>>(pK, pG, (float2*)d_out);
}

// Round 11
// 94.816 us; speedup vs baseline: 1.0887x; 1.0887x over previous
//
#include <hip/hip_runtime.h>

#define NAG   8192
#define NK    4096
#define BLOCK 256
#define ROWS  4               // agents per thread (register blocking)
#define CHUNK 128             // j-points staged per block
#define NCK   (NAG / CHUNK)   // 64 KDE chunks
#define NCG   (NK  / CHUNK)   // 32 GMM chunks
#define AGB   (BLOCK * ROWS)  // 1024 agents per block

// Pre-scale trick: exp(-d2/(2h^2)) = exp2(-|sK*dx|^2), sK = sqrt(log2e/(2h^2)).
// h = 0.05  -> sK = 16.98643615 ; s = 5/64 -> sG = 10.87131904
#define SK_SCALE 16.98643615f
#define SG_SCALE 10.87131904f
// out = (B/h^2 - C*N*h^2/s^4 + F*N*h^2/s^2)/A with B,C in prescaled coords:
#define SC_B   (23.5482041f)    // (1/h^2)/sK
#define SC_C   (50569.375f)     // (N*h^2/s^4)/sG
#define SC_F   (3355.4432f)     // N*h^2/s^2

typedef float f32x2 __attribute__((ext_vector_type(2)));

// VOP3P packed-f32: ALL vector operands must be 64-bit VGPR pairs on gfx950.
__device__ __forceinline__ f32x2 pk_add(f32x2 a, f32x2 b) {
  f32x2 d; asm("v_pk_add_f32 %0, %1, %2" : "=v"(d) : "v"(a), "v"(b)); return d;
}
__device__ __forceinline__ f32x2 pk_mul(f32x2 a, f32x2 b) {
  f32x2 d; asm("v_pk_mul_f32 %0, %1, %2" : "=v"(d) : "v"(a), "v"(b)); return d;
}
__device__ __forceinline__ f32x2 pk_fma(f32x2 a, f32x2 b, f32x2 c) {
  f32x2 d; asm("v_pk_fma_f32 %0, %1, %2, %3" : "=v"(d) : "v"(a), "v"(b), "v"(c));
  return d;
}
__device__ __forceinline__ f32x2 bcast(float a) { return (f32x2){a, a}; }

// ws: pK float4[NCK][NAG] (8 MB)   {A, Bx', By', 0}
//     pG float4[NCG][NAG] (4 MB)   {Cx', Cy', Fx, Fy}
__global__ __launch_bounds__(BLOCK) void wm_pair_kernel(
    const float*  __restrict__ t,
    const float2* __restrict__ X,
    const float2* __restrict__ m0,
    const float2* __restrict__ mv,
    const float*  __restrict__ w,
    float4* __restrict__ pK,
    float4* __restrict__ pG) {
  __shared__ float4 sGP[CHUNK];  // GMM: {-sG*m.x, -sG*m.y, mv.x, mv.y}; KDE reuses as f32x2[]
  __shared__ float  sLW[CHUNK];  // GMM: log2(w)

  const int iBase = blockIdx.x * AGB + threadIdx.x;
  const int c = blockIdx.y;

  if (c < NCK) {
    // ---------------- KDE chunk ----------------
    f32x2* sNP = reinterpret_cast<f32x2*>(sGP);
    const int base = c * CHUNK;
    if (threadIdx.x < CHUNK) {
      const float2 xj = X[base + threadIdx.x];
      sNP[threadIdx.x] = (f32x2){-SK_SCALE * xj.x, -SK_SCALE * xj.y};
    }
    __syncthreads();

    f32x2 xi[ROWS];
#pragma unroll
    for (int r = 0; r < ROWS; ++r) {
      const float2 v = X[iBase + r * BLOCK];
      xi[r] = (f32x2){SK_SCALE * v.x, SK_SCALE * v.y};
    }
    float A[ROWS];
    f32x2 B[ROWS];
#pragma unroll
    for (int r = 0; r < ROWS; ++r) { A[r] = 0.f; B[r] = (f32x2){0.f, 0.f}; }

#pragma unroll 4
    for (int j = 0; j < CHUNK; ++j) {
      const f32x2 p = sNP[j];                      // one ds_read_b64, reused 4x
#pragma unroll
      for (int r = 0; r < ROWS; ++r) {
        const f32x2 pd = pk_add(xi[r], p);         // sK*(Xi - Xj)
        const f32x2 sq = pk_mul(pd, pd);
        const float e  = __builtin_amdgcn_exp2f(-(sq.x + sq.y)); // neg folds into src mod
        A[r] += e;
        B[r] = pk_fma(bcast(e), pd, B[r]);
      }
    }
#pragma unroll
    for (int r = 0; r < ROWS; ++r)
      pK[c * NAG + iBase + r * BLOCK] = make_float4(A[r], B[r].x, B[r].y, 0.f);
  } else {
    // ---------------- GMM chunk ----------------
    // w folded into the exponent: gf = exp2(log2(w) - |sG(Xi-m)|^2) = w * exp(-d2/(2s^2))
    // (w in [0,1): log2(w) <= 0; w -> 0 gives -inf -> exp2 -> 0, correct.)
    const int cg = c - NCK;
    const int base = cg * CHUNK;
    if (threadIdx.x < CHUNK) {
      const float tt = t[0];
      const int j = base + threadIdx.x;
      const float2 m0j = m0[j];
      const float2 mvj = mv[j];
      sGP[threadIdx.x] = make_float4(-SG_SCALE * __builtin_fmaf(mvj.x, tt, m0j.x),
                                     -SG_SCALE * __builtin_fmaf(mvj.y, tt, m0j.y),
                                     mvj.x, mvj.y);
      sLW[threadIdx.x] = __log2f(w[j]);   // v_log_f32
    }
    __syncthreads();

    f32x2 xg[ROWS];
#pragma unroll
    for (int r = 0; r < ROWS; ++r) {
      const float2 v = X[iBase + r * BLOCK];
      xg[r] = (f32x2){SG_SCALE * v.x, SG_SCALE * v.y};
    }
    f32x2 C[ROWS], F[ROWS];
#pragma unroll
    for (int r = 0; r < ROWS; ++r) { C[r] = (f32x2){0.f, 0.f}; F[r] = (f32x2){0.f, 0.f}; }

#pragma unroll 4
    for (int j = 0; j < CHUNK; ++j) {
      const float4 p  = sGP[j];                    // one ds_read_b128, reused 4x
      const float lw  = sLW[j];                    // one ds_read_b32
      const f32x2 nm  = (f32x2){p.x, p.y};
      const f32x2 mj  = (f32x2){p.z, p.w};
#pragma unroll
      for (int r = 0; r < ROWS; ++r) {
        const f32x2 pd = pk_add(xg[r], nm);        // sG*(Xi - m)
        const f32x2 sq = pk_mul(pd, pd);
        const float gf = __builtin_amdgcn_exp2f(lw - sq.x - sq.y);
        const f32x2 gd = bcast(gf);
        C[r] = pk_fma(gd, pd, C[r]);
        F[r] = pk_fma(gd, mj, F[r]);
      }
    }
#pragma unroll
    for (int r = 0; r < ROWS; ++r)
      pG[cg * NAG + iBase + r * BLOCK] = make_float4(C[r].x, C[r].y, F[r].x, F[r].y);
  }
}

__global__ __launch_bounds__(64) void wm_final_kernel(
    const float4* __restrict__ pK, const float4* __restrict__ pG,
    float2* __restrict__ out) {
  const int i = blockIdx.x * 64 + threadIdx.x;   // 128 blocks x 64 threads = 8192
  float A = 0.f, Bx = 0.f, By = 0.f;
#pragma unroll 8
  for (int c = 0; c < NCK; ++c) {
    const float4 v = pK[c * NAG + i];
    A += v.x; Bx += v.y; By += v.z;
  }
  float Cx = 0.f, Cy = 0.f, Fx = 0.f, Fy = 0.f;
#pragma unroll 8
  for (int c = 0; c < NCG; ++c) {
    const float4 v = pG[c * NAG + i];
    Cx += v.x; Cy += v.y; Fx += v.z; Fy += v.w;
  }
  const float invA = 1.0f / A;   // A >= 1 (self term)
  const float ox = (SC_B * Bx - SC_C * Cx + SC_F * Fx) * invA;
  const float oy = (SC_B * By - SC_C * Cy + SC_F * Fy) * invA;
  out[i] = make_float2(ox, oy);
}

extern "C" void kernel_launch(void* const* d_in, const int* in_sizes, int n_in,
                              void* d_out, int out_size, void* d_ws, size_t ws_size,
                              hipStream_t stream) {
  const float*  t  = (const float*)d_in[0];
  const float2* X  = (const float2*)d_in[1];
  const float2* m0 = (const float2*)d_in[2];
  const float2* mv = (const float2*)d_in[3];
  const float*  w  = (const float*)d_in[4];
  float4* pK = (float4*)d_ws;
  float4* pG = (float4*)((char*)d_ws + (size_t)NCK * NAG * sizeof(float4));

  dim3 grid(NAG / AGB, NCK + NCG);   // 8 x 96 = 768 blocks
  wm_pair_kernel<<<grid, BLOCK, 0, stream>>>(t, X, m0, mv, w, pK, pG);
  wm_final_kernel<<<NAG / 64, 64, 0, stream>>>(pK, pG, (float2*)d_out);
}